// Round 8
// baseline (295.574 us; speedup 1.0000x reference)
//
#include <hip/hip_runtime.h>
#include <cstdint>
#include <cstddef>

// ---------------------------------------------------------------------------
// Zoner: out = softmax( mask ? -inf : tanh(zone@Wz+bz) . tanh(mean(txt)@Wt+bt) / sqrt(768) )
// B=32 L=80 Z=4096 D=768 DO=256.  Dominant cost: 402MB zone read (HBM floor ~64us).
// R3/R7 plateau at ~153us total (~3.2 TB/s GEMM) across 3 different schedules
//   -> schedule-independent => DRAM page re-activation from BK=64 column-slice
//   reads (256B per 1KB page per visit, 12 visits).
// R8: persistent blocks fetch FULL 1536B row-halves contiguously (page-dense),
//   decoupling fetch order (linear) from consume order (k-steps from LDS).
//   256 blocks x 512 thr, 1/CU; LDS 2x48KB dbuf + 2KB psum; 8 RG x 2 half-K
//   chunks; B = R7 fragment-order from L2 (reg dbuf); vmcnt never drained.
// ---------------------------------------------------------------------------

typedef float  f32x4  __attribute__((ext_vector_type(4)));
typedef __bf16 bf16x4 __attribute__((ext_vector_type(4)));
typedef __bf16 bf16x8 __attribute__((ext_vector_type(8)));

// workspace layout (bytes)
#define OFF_T     0         // t[32][256] fp32          (32 KB)
#define OFF_WZT   32768     // WzT fragment-order bf16, 196608 elems (384 KB)
#define OFF_FLAG  425984    // mask-format flag (int)
#define OFF_MP    426240    // mean partials [32][8][768] fp32 (768 KB)

__device__ __forceinline__ float fast_tanh(float x) {
    x = fminf(15.f, fmaxf(-15.f, x));
    float e2 = __expf(2.f * x);
    return (e2 - 1.f) * __builtin_amdgcn_rcpf(e2 + 1.f);
}

// ---------------------------------------------------------------------------
// prep1: blocks 0..255   : txt mean partial sums (b = blk>>3, 10 L-slices each)
//        blocks 256..319 : Wz -> fragment-order wzt
//          wzt[((kt*2+h)*16+g)*512 + lane*8 + e] = bf16(Wz[k][n])
//          with n = g*16 + (lane&15), k = kt*64 + h*32 + (lane>>4)*8 + e.
//        block  320      : mask dtype detector -> flag {0:int32,1:bytes,2:fp32,3:int64}
// ---------------------------------------------------------------------------
__global__ void prep1_kernel(const float* __restrict__ txt,
                             const float* __restrict__ Wz,
                             const void*  __restrict__ mask,
                             float* __restrict__ mp,
                             unsigned short* __restrict__ wzt,
                             int* __restrict__ flagp)
{
    const int blk = blockIdx.x, tid = threadIdx.x;
    if (blk < 256) {
        const int b = blk >> 3, part = blk & 7;
        const float* base = txt + (size_t)(b * 80 + part * 10) * 768;
        for (int d = tid; d < 768; d += 256) {
            float s = 0.f;
            #pragma unroll
            for (int l = 0; l < 10; ++l) s += base[l * 768 + d];
            mp[(b * 8 + part) * 768 + d] = s;
        }
    } else if (blk < 320) {
        const int i0 = (blk - 256) * 3072;
        for (int it = 0; it < 12; ++it) {
            int idx  = i0 + it * 256 + tid;      // 0..196607
            int e    = idx & 7;
            int lane = (idx >> 3) & 63;
            int slot = idx >> 9;                 // (kt*2+h)*16 + g
            int kt   = slot >> 5;
            int h    = (slot >> 4) & 1;
            int g    = slot & 15;
            int n    = g * 16 + (lane & 15);
            int k    = kt * 64 + h * 32 + (lane >> 4) * 8 + e;
            __bf16 v = (__bf16)Wz[k * 256 + n];
            wzt[idx] = __builtin_bit_cast(unsigned short, v);
        }
    } else {
        // scan first 32768 bytes (valid window for every candidate dtype)
        const unsigned* mw = (const unsigned*)mask;
        unsigned f_isf = 0, f_gt = 0, f_onz = 0, f_nz = 0;
        for (int i = tid; i < 8192; i += 256) {
            unsigned w = mw[i];
            if (w == 0x3F800000u) f_isf = 1;   // float 1.0 pattern
            else if (w > 1u)      f_gt  = 1;   // packed bool bytes
            if (w) { f_nz = 1; if (i & 1) f_onz = 1; }
        }
        __shared__ unsigned r[4];
        if (tid < 4) r[tid] = 0;
        __syncthreads();
        if (f_isf) atomicOr(&r[0], 1u);
        if (f_gt)  atomicOr(&r[1], 1u);
        if (f_onz) atomicOr(&r[2], 1u);
        if (f_nz)  atomicOr(&r[3], 1u);
        __syncthreads();
        if (tid == 0) {
            int flag;
            if (r[0])        flag = 2;   // fp32 0/1
            else if (r[1])   flag = 1;   // bytes
            else if (!r[3])  flag = 1;   // all-zero: byte path is always safe
            else if (!r[2])  flag = 3;   // nonzeros but all odd words zero -> int64
            else             flag = 0;   // int32
            *flagp = flag;
        }
    }
}

// ---------------------------------------------------------------------------
// prep2: mean = sum(partials)/80 ; t[b][o] = tanh(mean @ Wt + bt)   (fp32)
// ---------------------------------------------------------------------------
__global__ void prep2_kernel(const float* __restrict__ mp,
                             const float* __restrict__ Wt,
                             const float* __restrict__ bt,
                             float* __restrict__ tws)
{
    const int b = blockIdx.x, tid = threadIdx.x;
    __shared__ float meanv[768];
    for (int d = tid; d < 768; d += 256) {
        float s = 0.f;
        #pragma unroll
        for (int p = 0; p < 8; ++p) s += mp[(b * 8 + p) * 768 + d];
        meanv[d] = s * 0.0125f;   // 1/80
    }
    __syncthreads();
    float acc = bt[tid];
    for (int d = 0; d < 768; ++d) acc = fmaf(meanv[d], Wt[d * 256 + tid], acc);
    tws[b * 256 + tid] = tanhf(acc);
}

// ---------------------------------------------------------------------------
// Fused GEMM, persistent-stripe version.
// 256 blocks x 512 thr (8 waves), 1 block/CU. Block owns rows [blk*512,+512)
// = 8 row-groups (RG) of 64; each RG split into 2 half-K chunks (hp=0: k<384,
// hp=1: k>=384). Chunk fetch = 64 rows x 1536B CONTIGUOUS per row (96KB fp32)
// -> DRAM page-dense. LDS dbuf 2x48KB bf16 (row pitch 768B, XOR-swizzled).
// Per chunk: 6 k-steps x 16 MFMA/wave; wave wv owns cols [wv*32,+32): acc[4][2]
// carried across the RG's two chunks. B: R7 fragment-order wzt, breg dbuf.
// Sync: one lgkmcnt(0)+s_barrier per chunk; vmcnt NEVER drained (next chunk's
// 96KB stays in flight through compute+epilogue).
// ---------------------------------------------------------------------------
__global__ __launch_bounds__(512, 2)
void gemm_kernel(const float* __restrict__ zone,
                 const unsigned short* __restrict__ wzt,   // fragment-order B
                 const float* __restrict__ tws,
                 const float* __restrict__ bz,
                 float* __restrict__ out)
{
    __shared__ alignas(16) unsigned char smem[100352];  // 2*49152 + 2048 psum
    const int tid  = threadIdx.x;
    const int blk  = blockIdx.x;
    const int b    = blk >> 3;             // 8 blocks per batch
    const int lane = tid & 63;
    const int wv   = tid >> 6;             // wave 0..7; cols wv*32..+31
    const int l15  = lane & 15;
    const int l4   = lane >> 4;
    const int swz  = (l15 & 7) << 4;

    float* psum = (float*)(smem + 98304);
    const unsigned short* Bg = wzt + (size_t)lane * 8;
    const float* Zb = zone + (size_t)blk * 512 * 768;

    // t / bz per-wave columns (constant for the whole block)
    float tv[2], bzv[2];
    #pragma unroll
    for (int nt = 0; nt < 2; ++nt) {
        const int col = wv * 32 + nt * 16 + l15;
        tv[nt]  = tws[b * 256 + col];
        bzv[nt] = bz[col];
    }

    f32x4  acc[4][2];
    f32x4  vf[12];            // fetch staging: 96KB/block, 192B/thread
    bf16x8 breg[2][2][2];     // B dbuf [buf][nt][h]

    auto zero_acc = [&]() {
        #pragma unroll
        for (int i = 0; i < 4; ++i)
            #pragma unroll
            for (int j = 0; j < 2; ++j)
                acc[i][j] = f32x4{0.f, 0.f, 0.f, 0.f};
    };

    auto fetch_issue = [&](int c) {      // chunk c: rg=c>>1, hp=c&1
        const float* cb = Zb + (size_t)(c >> 1) * 64 * 768 + (c & 1) * 384;
        #pragma unroll
        for (int j = 0; j < 12; ++j) {
            const int u   = j * 512 + tid;     // 16B unit in [0,6144)
            const int row = u / 96;            // 96 units of 16B per 1536B row-half
            const int un  = u - row * 96;
            vf[j] = *(const f32x4*)(cb + (size_t)row * 768 + un * 4);
        }
    };
    auto convert_write = [&](int buf) {
        #pragma unroll
        for (int j = 0; j < 12; ++j) {
            const int u   = j * 512 + tid;
            const int row = u / 96;
            const int un  = u - row * 96;
            bf16x4 h = { (__bf16)vf[j][0], (__bf16)vf[j][1],
                         (__bf16)vf[j][2], (__bf16)vf[j][3] };
            *(bf16x4*)(smem + buf * 49152 + row * 768 +
                       ((un * 8) ^ ((row & 7) << 4))) = h;
        }
    };
    auto load_b = [&](int ktg, int buf) {
        #pragma unroll
        for (int nt = 0; nt < 2; ++nt)
            #pragma unroll
            for (int h = 0; h < 2; ++h)
                breg[buf][nt][h] = *(const bf16x8*)
                    (Bg + (size_t)((ktg * 2 + h) * 16 + (wv * 2 + nt)) * 512);
    };

    // ---- prologue: chunk 0 into buf 0; B(ktg=0) into breg[0] ----
    zero_acc();
    fetch_issue(0);
    __builtin_amdgcn_sched_barrier(0);
    load_b(0, 0);
    convert_write(0);                    // compiler waits vf as consumed
    asm volatile("s_waitcnt lgkmcnt(0)" ::: "memory");
    __builtin_amdgcn_s_barrier();
    __builtin_amdgcn_sched_barrier(0);

    // ---- chunk loop: 16 chunks (8 RG x 2 half-K) ----
    #pragma unroll 2
    for (int c = 0; c < 16; ++c) {
        if (c < 15) {
            fetch_issue(c + 1);                  // 96KB in flight through chunk
            __builtin_amdgcn_sched_barrier(0);
        }
        // compute: 6 k-steps from LDS buf[c&1]; B from breg (invariant:
        // entering chunk, breg[0] == B(ktg_first = (c&1)*6))
        {
            const unsigned bufbase = (unsigned)(c & 1) * 49152u;
            const int ktg0 = (c & 1) * 6;
            #pragma unroll
            for (int ks = 0; ks < 6; ++ks) {
                const int cur = ks & 1;
                bf16x8 af[4][2];
                #pragma unroll
                for (int rt = 0; rt < 4; ++rt) {
                    const unsigned rowb = bufbase + (rt * 16 + l15) * 768;
                    af[rt][0] = *(const bf16x8*)(smem + rowb + (unsigned)((ks * 128 + l4 * 16) ^ swz));
                    af[rt][1] = *(const bf16x8*)(smem + rowb + (unsigned)((ks * 128 + 64 + l4 * 16) ^ swz));
                }
                if (ks < 5)       load_b(ktg0 + ks + 1, cur ^ 1);
                else if (c < 15)  load_b(((c + 1) & 1) * 6, 0);   // next chunk's first
                #pragma unroll
                for (int rt = 0; rt < 4; ++rt)
                    #pragma unroll
                    for (int nt = 0; nt < 2; ++nt) {
                        acc[rt][nt] = __builtin_amdgcn_mfma_f32_16x16x32_bf16(af[rt][0], breg[cur][nt][0], acc[rt][nt], 0, 0, 0);
                        acc[rt][nt] = __builtin_amdgcn_mfma_f32_16x16x32_bf16(af[rt][1], breg[cur][nt][1], acc[rt][nt], 0, 0, 0);
                    }
            }
        }
        // epilogue after the RG's second chunk (VALU work also hides vf latency)
        if (c & 1) {
            float p[4][4];
            #pragma unroll
            for (int rt = 0; rt < 4; ++rt)
                #pragma unroll
                for (int r = 0; r < 4; ++r) {
                    float s = 0.f;
                    #pragma unroll
                    for (int nt = 0; nt < 2; ++nt)
                        s += fast_tanh(acc[rt][nt][r] + bzv[nt]) * tv[nt];
                    float v = s;
                    v += __shfl_xor(v, 1);
                    v += __shfl_xor(v, 2);
                    v += __shfl_xor(v, 4);
                    v += __shfl_xor(v, 8);
                    p[rt][r] = v;
                }
            if (l15 == 0) {
                #pragma unroll
                for (int rt = 0; rt < 4; ++rt)
                    #pragma unroll
                    for (int r = 0; r < 4; ++r)
                        psum[(rt * 16 + l4 * 4 + r) * 8 + wv] = p[rt][r];
            }
            asm volatile("s_waitcnt lgkmcnt(0)" ::: "memory");
            __builtin_amdgcn_s_barrier();
            if (tid < 64) {
                float s = 0.f;
                #pragma unroll
                for (int w = 0; w < 8; ++w) s += psum[tid * 8 + w];
                out[blk * 512 + (c >> 1) * 64 + tid] = s * 0.03608439182435161f; // 1/sqrt(768)
            }
            zero_acc();
        }
        if (c < 15)
            convert_write((c + 1) & 1);          // fill other buffer
        asm volatile("s_waitcnt lgkmcnt(0)" ::: "memory");
        __builtin_amdgcn_s_barrier();
        __builtin_amdgcn_sched_barrier(0);
    }
}

// ---------------------------------------------------------------------------
// softmax (in-place over d_out), one block per batch; mask applied per flag
// ---------------------------------------------------------------------------
__global__ void softmax_kernel(float* __restrict__ out,
                               const void* __restrict__ mask,
                               const int* __restrict__ flagp)
{
    const int b = blockIdx.x, tid = threadIdx.x;
    __shared__ float vals[4096];
    __shared__ float red[8];
    const int flag = *flagp;
    const int base = b << 12;
    float* po = out + base;
    float mx = -INFINITY;
    #pragma unroll
    for (int i = 0; i < 16; ++i) {
        const int z = i * 256 + tid;
        const int gi = base + z;
        bool msk;
        if (flag == 1)      msk = ((const unsigned char*)mask)[gi] != 0;
        else if (flag == 0) msk = ((const int*)mask)[gi] != 0;
        else if (flag == 2) msk = ((const float*)mask)[gi] != 0.f;
        else                msk = ((const long long*)mask)[gi] != 0;
        const float v = msk ? -INFINITY : po[z];
        vals[z] = v;
        mx = fmaxf(mx, v);
    }
    #pragma unroll
    for (int off = 32; off > 0; off >>= 1) mx = fmaxf(mx, __shfl_xor(mx, off));
    if ((tid & 63) == 0) red[tid >> 6] = mx;
    __syncthreads();
    mx = fmaxf(fmaxf(red[0], red[1]), fmaxf(red[2], red[3]));
    float s = 0.f;
    #pragma unroll
    for (int i = 0; i < 16; ++i) {
        const int z = i * 256 + tid;
        const float e = __expf(vals[z] - mx);   // -inf -> 0
        vals[z] = e;
        s += e;
    }
    #pragma unroll
    for (int off = 32; off > 0; off >>= 1) s += __shfl_xor(s, off);
    if ((tid & 63) == 0) red[4 + (tid >> 6)] = s;
    __syncthreads();
    const float inv = 1.f / (red[4] + red[5] + red[6] + red[7]);
    #pragma unroll
    for (int i = 0; i < 16; ++i) {
        const int z = i * 256 + tid;
        po[z] = vals[z] * inv;
    }
}

// ---------------------------------------------------------------------------
extern "C" void kernel_launch(void* const* d_in, const int* in_sizes, int n_in,
                              void* d_out, int out_size, void* d_ws, size_t ws_size,
                              hipStream_t stream)
{
    (void)in_sizes; (void)n_in; (void)out_size; (void)ws_size;
    const float* txt  = (const float*)d_in[0];
    const float* zone = (const float*)d_in[1];
    const void*  mask = d_in[2];
    const float* Wt   = (const float*)d_in[3];
    const float* bt   = (const float*)d_in[4];
    const float* Wz   = (const float*)d_in[5];
    const float* bz   = (const float*)d_in[6];
    float* out = (float*)d_out;
    char*  ws  = (char*)d_ws;
    float* tws           = (float*)(ws + OFF_T);
    unsigned short* wzt  = (unsigned short*)(ws + OFF_WZT);
    int*   flagp         = (int*)(ws + OFF_FLAG);
    float* mp            = (float*)(ws + OFF_MP);

    prep1_kernel<<<321, 256, 0, stream>>>(txt, Wz, mask, mp, wzt, flagp);
    prep2_kernel<<<32, 256, 0, stream>>>(mp, Wt, bt, tws);
    gemm_kernel<<<256, 512, 0, stream>>>(zone, wzt, tws, bz, out);
    softmax_kernel<<<32, 256, 0, stream>>>(out, mask, flagp);
}

// Round 9
// 168.121 us; speedup vs baseline: 1.7581x; 1.7581x over previous
//
#include <hip/hip_runtime.h>
#include <cstdint>
#include <cstddef>

// ---------------------------------------------------------------------------
// Zoner: out = softmax( mask ? -inf : tanh(zone@Wz+bz) . tanh(mean(txt)@Wt+bt) / sqrt(768) )
// B=32 L=80 Z=4096 D=768 DO=256.  Dominant cost: 402MB zone read (HBM floor ~64us).
// R3/R7: ~153us total (~3.2 TB/s GEMM), three schedules identical -> address-
//   pattern-limited, not schedule-limited.
// R8 (chunked persistent): 272us. Counters: FETCH=415MB (volume correct),
//   WRITE=46MB (!! scratch: VGPR capped 128, vf[12] spilled), occ 23%,
//   1 blk/CU lockstep. Implementation bugs, theory untested.
// R9: A-panel-resident blocks. BM=32, FULL K in LDS (48KB+1KB -> 3 blocks/CU,
//   24 waves). Fetch = 32 complete 3072B rows (max page density; each wave's
//   64x16B units sit inside one row). Staging live<=28 VGPR (no spill).
//   ONE barrier, then 12 barrier-free k-steps (LDS read-only; B reg-dbuf from
//   fragment-order wzt in L2). Inter-block overlap replaces waitcnt tricks.
// ---------------------------------------------------------------------------

typedef float  f32x4  __attribute__((ext_vector_type(4)));
typedef __bf16 bf16x4 __attribute__((ext_vector_type(4)));
typedef __bf16 bf16x8 __attribute__((ext_vector_type(8)));

// workspace layout (bytes)
#define OFF_T     0         // t[32][256] fp32          (32 KB)
#define OFF_WZT   32768     // WzT fragment-order bf16, 196608 elems (384 KB)
#define OFF_FLAG  425984    // mask-format flag (int)
#define OFF_MP    426240    // mean partials [32][8][768] fp32 (768 KB)

__device__ __forceinline__ float fast_tanh(float x) {
    x = fminf(15.f, fmaxf(-15.f, x));
    float e2 = __expf(2.f * x);
    return (e2 - 1.f) * __builtin_amdgcn_rcpf(e2 + 1.f);
}

// ---------------------------------------------------------------------------
// prep1: blocks 0..255   : txt mean partial sums (b = blk>>3, 10 L-slices each)
//        blocks 256..319 : Wz -> fragment-order wzt
//          wzt[((kt*2+h)*16+g)*512 + lane*8 + e] = bf16(Wz[k][n])
//          with n = g*16 + (lane&15), k = kt*64 + h*32 + (lane>>4)*8 + e.
//        block  320      : mask dtype detector -> flag {0:int32,1:bytes,2:fp32,3:int64}
// ---------------------------------------------------------------------------
__global__ void prep1_kernel(const float* __restrict__ txt,
                             const float* __restrict__ Wz,
                             const void*  __restrict__ mask,
                             float* __restrict__ mp,
                             unsigned short* __restrict__ wzt,
                             int* __restrict__ flagp)
{
    const int blk = blockIdx.x, tid = threadIdx.x;
    if (blk < 256) {
        const int b = blk >> 3, part = blk & 7;
        const float* base = txt + (size_t)(b * 80 + part * 10) * 768;
        for (int d = tid; d < 768; d += 256) {
            float s = 0.f;
            #pragma unroll
            for (int l = 0; l < 10; ++l) s += base[l * 768 + d];
            mp[(b * 8 + part) * 768 + d] = s;
        }
    } else if (blk < 320) {
        const int i0 = (blk - 256) * 3072;
        for (int it = 0; it < 12; ++it) {
            int idx  = i0 + it * 256 + tid;      // 0..196607
            int e    = idx & 7;
            int lane = (idx >> 3) & 63;
            int slot = idx >> 9;                 // (kt*2+h)*16 + g
            int kt   = slot >> 5;
            int h    = (slot >> 4) & 1;
            int g    = slot & 15;
            int n    = g * 16 + (lane & 15);
            int k    = kt * 64 + h * 32 + (lane >> 4) * 8 + e;
            __bf16 v = (__bf16)Wz[k * 256 + n];
            wzt[idx] = __builtin_bit_cast(unsigned short, v);
        }
    } else {
        // scan first 32768 bytes (valid window for every candidate dtype)
        const unsigned* mw = (const unsigned*)mask;
        unsigned f_isf = 0, f_gt = 0, f_onz = 0, f_nz = 0;
        for (int i = tid; i < 8192; i += 256) {
            unsigned w = mw[i];
            if (w == 0x3F800000u) f_isf = 1;   // float 1.0 pattern
            else if (w > 1u)      f_gt  = 1;   // packed bool bytes
            if (w) { f_nz = 1; if (i & 1) f_onz = 1; }
        }
        __shared__ unsigned r[4];
        if (tid < 4) r[tid] = 0;
        __syncthreads();
        if (f_isf) atomicOr(&r[0], 1u);
        if (f_gt)  atomicOr(&r[1], 1u);
        if (f_onz) atomicOr(&r[2], 1u);
        if (f_nz)  atomicOr(&r[3], 1u);
        __syncthreads();
        if (tid == 0) {
            int flag;
            if (r[0])        flag = 2;   // fp32 0/1
            else if (r[1])   flag = 1;   // bytes
            else if (!r[3])  flag = 1;   // all-zero: byte path is always safe
            else if (!r[2])  flag = 3;   // nonzeros but all odd words zero -> int64
            else             flag = 0;   // int32
            *flagp = flag;
        }
    }
}

// ---------------------------------------------------------------------------
// prep2: mean = sum(partials)/80 ; t[b][o] = tanh(mean @ Wt + bt)   (fp32)
// ---------------------------------------------------------------------------
__global__ void prep2_kernel(const float* __restrict__ mp,
                             const float* __restrict__ Wt,
                             const float* __restrict__ bt,
                             float* __restrict__ tws)
{
    const int b = blockIdx.x, tid = threadIdx.x;
    __shared__ float meanv[768];
    for (int d = tid; d < 768; d += 256) {
        float s = 0.f;
        #pragma unroll
        for (int p = 0; p < 8; ++p) s += mp[(b * 8 + p) * 768 + d];
        meanv[d] = s * 0.0125f;   // 1/80
    }
    __syncthreads();
    float acc = bt[tid];
    for (int d = 0; d < 768; ++d) acc = fmaf(meanv[d], Wt[d * 256 + tid], acc);
    tws[b * 256 + tid] = tanhf(acc);
}

// ---------------------------------------------------------------------------
// Fused GEMM, A-panel-resident version.
// 4096 blocks x 512 thr (8 waves); block owns 32 rows, FULL K=768 in LDS
// (32x768 bf16 = 48KB, XOR-swizzled, + 1KB psum -> 3 blocks/CU, 24 waves/CU).
// Phase 1: fetch 32 complete rows (3072B contiguous each; wave units never
//   cross a row: 192 units/row = 3 waves). 6+6 rotating staging (live<=28 VGPR).
// Phase 2 (after ONE barrier): 12 k-steps, barrier-free. Wave wv owns
//   32 rows x cols [wv*32,+32): acc[2][2]. B: fragment-order wzt (L2), reg dbuf.
// Phase 3: tanh/dot/reduce epilogue, psum in LDS, 32 outputs.
// ---------------------------------------------------------------------------
__global__ __launch_bounds__(512)
void gemm_kernel(const float* __restrict__ zone,
                 const unsigned short* __restrict__ wzt,   // fragment-order B
                 const float* __restrict__ tws,
                 const float* __restrict__ bz,
                 float* __restrict__ out)
{
    __shared__ alignas(16) unsigned char smem[50176];   // 48KB panel + 1KB psum
    const int tid  = threadIdx.x;
    const int blk  = blockIdx.x;
    const int b    = blk >> 7;             // 128 blocks per batch
    const int lane = tid & 63;
    const int wv   = tid >> 6;             // wave 0..7; cols wv*32..+31
    const int l15  = lane & 15;
    const int l4   = lane >> 4;

    float* psum = (float*)(smem + 49152);
    const unsigned short* Bg = wzt + (size_t)lane * 8;
    const float* Zb = zone + (size_t)blk * 32 * 768;

    // ---- phase 1: panel fetch (32 rows x 3072B contiguous) ----
    // unit u = p*512 + tid (16B fp32 -> 8B bf16); row = u/192, un = u%192.
    {
        auto g_load = [&](int p) -> f32x4 {
            const int u   = p * 512 + tid;
            const int row = u / 192;
            const int un  = u - row * 192;
            return *(const f32x4*)(Zb + (size_t)row * 768 + un * 4);
        };
        auto l_write = [&](int p, f32x4 v) {
            const int u   = p * 512 + tid;
            const int row = u / 192;
            const int un  = u - row * 192;
            bf16x4 h = { (__bf16)v[0], (__bf16)v[1], (__bf16)v[2], (__bf16)v[3] };
            *(bf16x4*)(smem + row * 1536 + ((un * 8) ^ ((row & 7) << 4))) = h;
        };
        f32x4 v0 = g_load(0), v1 = g_load(1), v2 = g_load(2);
        f32x4 v3 = g_load(3), v4 = g_load(4), v5 = g_load(5);
        f32x4 n0 = g_load(6);  l_write(0, v0);
        f32x4 n1 = g_load(7);  l_write(1, v1);
        f32x4 n2 = g_load(8);  l_write(2, v2);
        f32x4 n3 = g_load(9);  l_write(3, v3);
        f32x4 n4 = g_load(10); l_write(4, v4);
        f32x4 n5 = g_load(11); l_write(5, v5);
        l_write(6, n0); l_write(7, n1); l_write(8,  n2);
        l_write(9, n3); l_write(10, n4); l_write(11, n5);
    }
    __syncthreads();

    // ---- phase 2: 12 k-steps, barrier-free ----
    f32x4 acc[2][2];
    #pragma unroll
    for (int i = 0; i < 2; ++i)
        #pragma unroll
        for (int j = 0; j < 2; ++j)
            acc[i][j] = f32x4{0.f, 0.f, 0.f, 0.f};

    bf16x8 breg[2][2][2];     // [buf][nt][h]
    auto load_b = [&](int ks, int buf) {
        #pragma unroll
        for (int nt = 0; nt < 2; ++nt)
            #pragma unroll
            for (int h = 0; h < 2; ++h)
                breg[buf][nt][h] = *(const bf16x8*)
                    (Bg + (size_t)((ks * 2 + h) * 16 + (wv * 2 + nt)) * 512);
    };

    load_b(0, 0);
    const int swz = (l15 & 7) << 4;
    #pragma unroll
    for (int ks = 0; ks < 12; ++ks) {
        const int cur = ks & 1;
        if (ks < 11) load_b(ks + 1, cur ^ 1);   // L2 latency hides under LDS+MFMA
        bf16x8 af[2][2];
        #pragma unroll
        for (int rt = 0; rt < 2; ++rt) {
            const unsigned rowb = (rt * 16 + l15) * 1536;
            af[rt][0] = *(const bf16x8*)(smem + rowb + (unsigned)((ks * 128 + l4 * 16) ^ swz));
            af[rt][1] = *(const bf16x8*)(smem + rowb + (unsigned)((ks * 128 + 64 + l4 * 16) ^ swz));
        }
        #pragma unroll
        for (int rt = 0; rt < 2; ++rt)
            #pragma unroll
            for (int nt = 0; nt < 2; ++nt) {
                acc[rt][nt] = __builtin_amdgcn_mfma_f32_16x16x32_bf16(af[rt][0], breg[cur][nt][0], acc[rt][nt], 0, 0, 0);
                acc[rt][nt] = __builtin_amdgcn_mfma_f32_16x16x32_bf16(af[rt][1], breg[cur][nt][1], acc[rt][nt], 0, 0, 0);
            }
    }

    // ---- phase 3: epilogue tanh(+bz).t, reduce over N ----
    // C/D layout: col = l15 (+nt*16+wv*32), row = l4*4 + r (+rt*16)
    float tv[2], bzv[2];
    #pragma unroll
    for (int nt = 0; nt < 2; ++nt) {
        const int col = wv * 32 + nt * 16 + l15;
        tv[nt]  = tws[b * 256 + col];
        bzv[nt] = bz[col];
    }
    float p[2][4];
    #pragma unroll
    for (int rt = 0; rt < 2; ++rt)
        #pragma unroll
        for (int r = 0; r < 4; ++r) {
            float s = 0.f;
            #pragma unroll
            for (int nt = 0; nt < 2; ++nt)
                s += fast_tanh(acc[rt][nt][r] + bzv[nt]) * tv[nt];
            float v = s;
            v += __shfl_xor(v, 1);
            v += __shfl_xor(v, 2);
            v += __shfl_xor(v, 4);
            v += __shfl_xor(v, 8);
            p[rt][r] = v;
        }
    if (l15 == 0) {
        #pragma unroll
        for (int rt = 0; rt < 2; ++rt)
            #pragma unroll
            for (int r = 0; r < 4; ++r)
                psum[(rt * 16 + l4 * 4 + r) * 8 + wv] = p[rt][r];
    }
    __syncthreads();
    if (tid < 32) {
        float s = 0.f;
        #pragma unroll
        for (int w = 0; w < 8; ++w) s += psum[tid * 8 + w];
        out[blk * 32 + tid] = s * 0.03608439182435161f;   // 1/sqrt(768)
    }
}

// ---------------------------------------------------------------------------
// softmax (in-place over d_out), one block per batch; mask applied per flag
// ---------------------------------------------------------------------------
__global__ void softmax_kernel(float* __restrict__ out,
                               const void* __restrict__ mask,
                               const int* __restrict__ flagp)
{
    const int b = blockIdx.x, tid = threadIdx.x;
    __shared__ float vals[4096];
    __shared__ float red[8];
    const int flag = *flagp;
    const int base = b << 12;
    float* po = out + base;
    float mx = -INFINITY;
    #pragma unroll
    for (int i = 0; i < 16; ++i) {
        const int z = i * 256 + tid;
        const int gi = base + z;
        bool msk;
        if (flag == 1)      msk = ((const unsigned char*)mask)[gi] != 0;
        else if (flag == 0) msk = ((const int*)mask)[gi] != 0;
        else if (flag == 2) msk = ((const float*)mask)[gi] != 0.f;
        else                msk = ((const long long*)mask)[gi] != 0;
        const float v = msk ? -INFINITY : po[z];
        vals[z] = v;
        mx = fmaxf(mx, v);
    }
    #pragma unroll
    for (int off = 32; off > 0; off >>= 1) mx = fmaxf(mx, __shfl_xor(mx, off));
    if ((tid & 63) == 0) red[tid >> 6] = mx;
    __syncthreads();
    mx = fmaxf(fmaxf(red[0], red[1]), fmaxf(red[2], red[3]));
    float s = 0.f;
    #pragma unroll
    for (int i = 0; i < 16; ++i) {
        const int z = i * 256 + tid;
        const float e = __expf(vals[z] - mx);   // -inf -> 0
        vals[z] = e;
        s += e;
    }
    #pragma unroll
    for (int off = 32; off > 0; off >>= 1) s += __shfl_xor(s, off);
    if ((tid & 63) == 0) red[4 + (tid >> 6)] = s;
    __syncthreads();
    const float inv = 1.f / (red[4] + red[5] + red[6] + red[7]);
    #pragma unroll
    for (int i = 0; i < 16; ++i) {
        const int z = i * 256 + tid;
        po[z] = vals[z] * inv;
    }
}

// ---------------------------------------------------------------------------
extern "C" void kernel_launch(void* const* d_in, const int* in_sizes, int n_in,
                              void* d_out, int out_size, void* d_ws, size_t ws_size,
                              hipStream_t stream)
{
    (void)in_sizes; (void)n_in; (void)out_size; (void)ws_size;
    const float* txt  = (const float*)d_in[0];
    const float* zone = (const float*)d_in[1];
    const void*  mask = d_in[2];
    const float* Wt   = (const float*)d_in[3];
    const float* bt   = (const float*)d_in[4];
    const float* Wz   = (const float*)d_in[5];
    const float* bz   = (const float*)d_in[6];
    float* out = (float*)d_out;
    char*  ws  = (char*)d_ws;
    float* tws           = (float*)(ws + OFF_T);
    unsigned short* wzt  = (unsigned short*)(ws + OFF_WZT);
    int*   flagp         = (int*)(ws + OFF_FLAG);
    float* mp            = (float*)(ws + OFF_MP);

    prep1_kernel<<<321, 256, 0, stream>>>(txt, Wz, mask, mp, wzt, flagp);
    prep2_kernel<<<32, 256, 0, stream>>>(mp, Wt, bt, tws);
    gemm_kernel<<<4096, 512, 0, stream>>>(zone, wzt, tws, bz, out);
    softmax_kernel<<<32, 256, 0, stream>>>(out, mask, flagp);
}